// Round 6
// baseline (2257.639 us; speedup 1.0000x reference)
//
#include <hip/hip_runtime.h>
#include <math.h>

#define N_NODES 100000
#define LN_EPS 1e-5f
#define NBUCK ((N_NODES + 127) / 128)  // 782 buckets of 128 nodes
#define EPB 8192                        // edges per block in count/place
#define ROWP 65                         // LDS row stride (f32) -> conflict-free

typedef __attribute__((ext_vector_type(8))) short bf16x8;
typedef __attribute__((ext_vector_type(4))) float f32x4;

__device__ __forceinline__ unsigned short f2bf(float f) {
    unsigned int u = __float_as_uint(f);
    return (unsigned short)((u + 0x7FFFu + ((u >> 16) & 1u)) >> 16);
}
__device__ __forceinline__ float bf2f(unsigned short u) {
    return __uint_as_float(((unsigned int)u) << 16);
}

// ======== atomic-free edge bucketing (counting sort by 128-node bucket) ========
// R1 lesson: global atomics cost ~42B HBM write per edge. All conflict
// resolution in LDS; deterministic slabs via scans.

// K1: per-block histogram of dst buckets -> counts[blk][bucket]
__global__ void count_edges(const int* __restrict__ dst, int* __restrict__ counts, int E) {
    __shared__ int hist[NBUCK];
    for (int b = threadIdx.x; b < NBUCK; b += 512) hist[b] = 0;
    __syncthreads();
    int e0 = blockIdx.x * EPB;
#pragma unroll 4
    for (int i = 0; i < EPB / 512; ++i) {
        int e = e0 + i * 512 + (int)threadIdx.x;
        if (e < E) atomicAdd(&hist[((unsigned)dst[e]) >> 7], 1);
    }
    __syncthreads();
    for (int b = threadIdx.x; b < NBUCK; b += 512)
        counts[blockIdx.x * NBUCK + b] = hist[b];
}

// K2: per-bucket exclusive scan across blocks -> pos[blk][bucket], tot[bucket]
__global__ void scan_pos(const int* __restrict__ counts, int* __restrict__ pos,
                         int* __restrict__ tot, int nblk) {
    __shared__ int s[512];
    int b = blockIdx.x, i = threadIdx.x;
    int v = (i < nblk) ? counts[i * NBUCK + b] : 0;
    s[i] = v;
    __syncthreads();
    for (int off = 1; off < 512; off <<= 1) {
        int t = (i >= off) ? s[i - off] : 0;
        __syncthreads();
        s[i] += t;
        __syncthreads();
    }
    if (i < nblk) pos[i * NBUCK + b] = s[i] - v;
    if (i == 511) tot[b] = s[511];
}

// K3: exclusive scan of bucket totals (1024 threads, NBUCK<=1024) -> base[], base[NBUCK]=E
__global__ void scan_base(const int* __restrict__ tot, int* __restrict__ base, int E) {
    __shared__ int s[1024];
    int i = threadIdx.x;
    int v = (i < NBUCK) ? tot[i] : 0;
    s[i] = v;
    __syncthreads();
    for (int off = 1; off < 1024; off <<= 1) {
        int t = (i >= off) ? s[i - off] : 0;
        __syncthreads();
        s[i] += t;
        __syncthreads();
    }
    if (i < NBUCK) base[i] = s[i] - v;
    if (i == 0) base[NBUCK] = E;
}

// K4: place edges into per-(block,bucket) disjoint slabs via LDS cursors.
// Packed entry: (dst&127)<<24 | src  (src < 2^17 < 2^24).
__global__ void place_edges(const int* __restrict__ src, const int* __restrict__ dst,
                            const int* __restrict__ pos, const int* __restrict__ base,
                            unsigned* __restrict__ bucket, int E) {
    __shared__ int lcur[NBUCK];
    for (int b = threadIdx.x; b < NBUCK; b += 512)
        lcur[b] = pos[blockIdx.x * NBUCK + b] + base[b];
    __syncthreads();
    int e0 = blockIdx.x * EPB;
#pragma unroll 4
    for (int i = 0; i < EPB / 512; ++i) {
        int e = e0 + i * 512 + (int)threadIdx.x;
        if (e < E) {
            unsigned d = (unsigned)dst[e];
            unsigned s = (unsigned)src[e];
            int p = atomicAdd(&lcur[d >> 7], 1);
            bucket[p] = ((d & 127u) << 24) | s;
        }
    }
}

// K5: per-bucket degree histogram -> dinv (no csr/offsets needed anymore)
__global__ void deg_dinv(const unsigned* __restrict__ bucket, const int* __restrict__ base,
                         float* __restrict__ dinv, int n) {
    __shared__ int hist[128];
    int b = blockIdx.x, t = threadIdx.x;
    if (t < 128) hist[t] = 0;
    __syncthreads();
    int s0 = base[b], s1 = base[b + 1];
    for (int e = s0 + t; e < s1; e += 256)
        atomicAdd(&hist[bucket[e] >> 24], 1);
    __syncthreads();
    int node = (b << 7) + t;
    if (t < 128 && node < n) dinv[node] = rsqrtf((float)hist[t] + 1.f);
}

// ---------------- MFMA bf16 gemm: Y = X[n,K] @ W[K,OUT] (+bias, +LN+ELU, +dinv row scale) ----
template <int K, int OUT, bool LN, bool BIAS, bool AF32, bool OF32, bool SCALED>
__launch_bounds__(256)
__global__ void mfma_gemm(const void* __restrict__ Xv, const float* __restrict__ W,
                          const float* __restrict__ bias, const float* __restrict__ gamma,
                          const float* __restrict__ beta, void* __restrict__ Yv, int n,
                          const float* __restrict__ dinvp) {
    constexpr int T  = OUT / 16;
    constexpr int KP = K + 8;

    __shared__ __align__(16) unsigned short sWT[OUT * KP];  // W^T bf16
    for (int i = threadIdx.x; i < K * OUT; i += 256) {
        int k = i / OUT, o = i - k * OUT;
        sWT[o * KP + k] = f2bf(W[i]);
    }
    __syncthreads();

    int wv = threadIdx.x >> 6, lane = threadIdx.x & 63;
    int quad = lane >> 4, l16 = lane & 15;
    int m0 = (blockIdx.x * 4 + wv) * 16;
    int rowc = min(m0 + l16, n - 1);

    f32x4 acc[T];
#pragma unroll
    for (int t = 0; t < T; ++t) acc[t] = (f32x4){0.f, 0.f, 0.f, 0.f};

#pragma unroll
    for (int s = 0; s < K / 32; ++s) {
        int koff = s * 32 + quad * 8;
        bf16x8 af;
        if (AF32) {
            const float4* X4 = (const float4*)Xv;
            size_t base = ((size_t)rowc * K + koff) >> 2;
            float4 a0 = X4[base];
            float4 a1 = X4[base + 1];
            af[0] = (short)f2bf(a0.x); af[1] = (short)f2bf(a0.y);
            af[2] = (short)f2bf(a0.z); af[3] = (short)f2bf(a0.w);
            af[4] = (short)f2bf(a1.x); af[5] = (short)f2bf(a1.y);
            af[6] = (short)f2bf(a1.z); af[7] = (short)f2bf(a1.w);
        } else {
            const unsigned short* Xb = (const unsigned short*)Xv;
            af = *(const bf16x8*)(Xb + (size_t)rowc * K + koff);
        }
#pragma unroll
        for (int t = 0; t < T; ++t) {
            const bf16x8 bfrag = *(const bf16x8*)&sWT[(t * 16 + l16) * KP + koff];
            acc[t] = __builtin_amdgcn_mfma_f32_16x16x32_bf16(af, bfrag, acc[t], 0, 0, 0);
        }
    }

    float bj[T], gj[T], btj[T];
#pragma unroll
    for (int t = 0; t < T; ++t) {
        int c = t * 16 + l16;
        bj[t]  = BIAS ? bias[c] : 0.f;
        gj[t]  = LN ? gamma[c] : 1.f;
        btj[t] = LN ? beta[c] : 0.f;
    }

    float* Yf = (float*)Yv;
    unsigned short* Yb = (unsigned short*)Yv;

    if (LN) {
        float s[4] = {0.f, 0.f, 0.f, 0.f}, sq[4] = {0.f, 0.f, 0.f, 0.f};
#pragma unroll
        for (int t = 0; t < T; ++t)
#pragma unroll
            for (int r = 0; r < 4; ++r) {
                float v = acc[t][r] + bj[t];
                s[r] += v;
                sq[r] += v * v;
            }
#pragma unroll
        for (int off = 1; off < 16; off <<= 1)
#pragma unroll
            for (int r = 0; r < 4; ++r) {
                s[r] += __shfl_xor(s[r], off, 64);
                sq[r] += __shfl_xor(sq[r], off, 64);
            }
        float mu[4], rs[4];
#pragma unroll
        for (int r = 0; r < 4; ++r) {
            mu[r] = s[r] / OUT;
            float var = sq[r] / OUT - mu[r] * mu[r];
            rs[r] = rsqrtf(var + LN_EPS);
        }
#pragma unroll
        for (int r = 0; r < 4; ++r) {
            int rowg = m0 + quad * 4 + r;
            if (rowg < n) {
                float dv = SCALED ? dinvp[rowg] : 1.f;
#pragma unroll
                for (int t = 0; t < T; ++t) {
                    float y = (acc[t][r] + bj[t] - mu[r]) * rs[r] * gj[t] + btj[t];
                    y = y > 0.f ? y : expm1f(y);
                    if (SCALED) y *= dv;
                    size_t idx = (size_t)rowg * OUT + t * 16 + l16;
                    if (OF32) Yf[idx] = y; else Yb[idx] = f2bf(y);
                }
            }
        }
    } else {
#pragma unroll
        for (int r = 0; r < 4; ++r) {
            int rowg = m0 + quad * 4 + r;
            if (rowg < n) {
                float dv = SCALED ? dinvp[rowg] : 1.f;
#pragma unroll
                for (int t = 0; t < T; ++t) {
                    float y = acc[t][r] + bj[t];
                    if (SCALED) y *= dv;
                    size_t idx = (size_t)rowg * OUT + t * 16 + l16;
                    if (OF32) Yf[idx] = y; else Yb[idx] = f2bf(y);
                }
            }
        }
    }
}

// ---------------- gather v6: edge-centric, LDS accumulation per bucket ----------------
// R5 post-mortem: one-wave-per-node has a ~60us floor — VALUBusy 83%, cost is
// per-edge address chains + per-node epilogue (12 permute waits) + degree
// imbalance + cross-wave reduce. v6: one block per 128-node bucket; waves
// sweep the CONTIGUOUS bucket slab; per edge: readlane -> SALU row addr ->
// wave-wide 128B row load (16-deep batches) -> 1 shift + 1 ds_add_f32 into
// acc[dloc][feat] (stride 65 -> conflict-free). Perfect edge balance, zero
// per-node loop overhead, no csr/offsets at all. LN fused on the LDS rows.
// Input xs PRE-SCALED by dinv[row]:
//   out = dinv[node] * (sum_{s in N(node)} xs[s] + xs[node])
template <bool LN, bool SCALEOUT>
__launch_bounds__(256)
__global__ void gather_lds(const unsigned short* __restrict__ xs, const unsigned* __restrict__ bucket,
                           const int* __restrict__ base, const float* __restrict__ dinv,
                           const float* __restrict__ bias, const float* __restrict__ gamma,
                           const float* __restrict__ beta, unsigned short* __restrict__ out, int n) {
    __shared__ float acc[129 * ROWP];  // 128 nodes + trash row 128
    int t = threadIdx.x, lane = t & 63, wave = t >> 6;
    int b = blockIdx.x, r0 = b << 7;

    for (int i = t; i < 129 * ROWP; i += 256) acc[i] = 0.f;
    __syncthreads();

    int s0 = base[b], s1 = base[b + 1];
    for (int e0 = s0 + wave * 64; e0 < s1; e0 += 256) {
        int m = min(64, s1 - e0);
        unsigned myU = (lane < m) ? bucket[e0 + lane] : 0u;
        for (int k = 0; k < m; k += 16) {
            unsigned short v[16];
            int dl[16];
            // issue: 16 wave-wide row loads back-to-back (scalar base, no waits)
#pragma unroll
            for (int j = 0; j < 16; ++j) {
                int e = k + j;                       // wave-uniform
                int idx = (e < m) ? e : 0;           // clamp to valid edge
                unsigned u = (unsigned)__builtin_amdgcn_readlane((int)myU, idx);
                dl[j] = (e < m) ? (int)(u >> 24) : 128;  // 128 = trash row
                v[j] = xs[((size_t)(u & 0xFFFFFFu) << 6) + lane];
            }
            // consume: shift + LDS atomic add (consecutive lanes: conflict-free)
#pragma unroll
            for (int j = 0; j < 16; ++j)
                atomicAdd(&acc[dl[j] * ROWP + lane], bf2f(v[j]));
        }
    }
    __syncthreads();

    // LN/output phase: 2 threads per node (halves of the 64-feature row)
    int nl = t >> 1, half = t & 1;
    int node = r0 + nl;
    if (node >= n) return;
    float dd = dinv[node];
    int c0 = half << 5;

    unsigned su[16];
    {
        const uint4* sp = (const uint4*)(xs + (((size_t)node) << 6) + c0);
        *(uint4*)&su[0]  = sp[0];
        *(uint4*)&su[4]  = sp[1];
        *(uint4*)&su[8]  = sp[2];
        *(uint4*)&su[12] = sp[3];
    }
    float y[32];
#pragma unroll
    for (int k = 0; k < 32; ++k) {
        unsigned w = su[k >> 1];
        float sf = (k & 1) ? __uint_as_float(w & 0xFFFF0000u) : __uint_as_float(w << 16);
        y[k] = (acc[nl * ROWP + c0 + k] + sf) * dd;
    }

    unsigned o[16];
    if (!LN) {
#pragma unroll
        for (int k = 0; k < 16; ++k)
            o[k] = (unsigned)f2bf(y[2 * k]) | ((unsigned)f2bf(y[2 * k + 1]) << 16);
    } else {
        const float4* bp = (const float4*)(bias + c0);
        float s = 0.f, sq = 0.f;
#pragma unroll
        for (int kk = 0; kk < 8; ++kk) {
            float4 b4 = bp[kk];
            y[4 * kk + 0] += b4.x; y[4 * kk + 1] += b4.y;
            y[4 * kk + 2] += b4.z; y[4 * kk + 3] += b4.w;
        }
#pragma unroll
        for (int k = 0; k < 32; ++k) { s += y[k]; sq += y[k] * y[k]; }
        s += __shfl_xor(s, 1, 64);
        sq += __shfl_xor(sq, 1, 64);
        float mu = s * (1.f / 64.f);
        float var = sq * (1.f / 64.f) - mu * mu;
        float rs = rsqrtf(var + LN_EPS);
        const float4* gp = (const float4*)(gamma + c0);
        const float4* tp = (const float4*)(beta + c0);
#pragma unroll
        for (int kk = 0; kk < 8; ++kk) {
            float4 g4 = gp[kk];
            float4 t4 = tp[kk];
            float z0 = (y[4 * kk + 0] - mu) * rs * g4.x + t4.x;
            float z1 = (y[4 * kk + 1] - mu) * rs * g4.y + t4.y;
            float z2 = (y[4 * kk + 2] - mu) * rs * g4.z + t4.z;
            float z3 = (y[4 * kk + 3] - mu) * rs * g4.w + t4.w;
            z0 = z0 > 0.f ? z0 : expm1f(z0);
            z1 = z1 > 0.f ? z1 : expm1f(z1);
            z2 = z2 > 0.f ? z2 : expm1f(z2);
            z3 = z3 > 0.f ? z3 : expm1f(z3);
            if (SCALEOUT) { z0 *= dd; z1 *= dd; z2 *= dd; z3 *= dd; }
            o[2 * kk]     = (unsigned)f2bf(z0) | ((unsigned)f2bf(z1) << 16);
            o[2 * kk + 1] = (unsigned)f2bf(z2) | ((unsigned)f2bf(z3) << 16);
        }
    }
    uint4* op = (uint4*)(out + (((size_t)node) << 6) + c0);
    op[0] = *(uint4*)&o[0];
    op[1] = *(uint4*)&o[4];
    op[2] = *(uint4*)&o[8];
    op[3] = *(uint4*)&o[12];
}

extern "C" void kernel_launch(void* const* d_in, const int* in_sizes, int n_in,
                              void* d_out, int out_size, void* d_ws, size_t ws_size,
                              hipStream_t stream) {
    const float* x  = (const float*)d_in[0];
    const int* ei   = (const int*)d_in[1];
    const float* W1 = (const float*)d_in[2];
    const float* b1 = (const float*)d_in[3];
    const float* g1 = (const float*)d_in[4];
    const float* be1= (const float*)d_in[5];
    const float* W2 = (const float*)d_in[6];
    const float* b2 = (const float*)d_in[7];
    const float* g2 = (const float*)d_in[8];
    const float* be2= (const float*)d_in[9];
    const float* W3 = (const float*)d_in[10];
    const float* b3 = (const float*)d_in[11];
    const float* g3 = (const float*)d_in[12];
    const float* be3= (const float*)d_in[13];
    const float* lw1= (const float*)d_in[14];
    const float* lb1= (const float*)d_in[15];
    const float* g4 = (const float*)d_in[16];
    const float* be4= (const float*)d_in[17];
    const float* lw2= (const float*)d_in[18];
    const float* lb2= (const float*)d_in[19];
    float* out = (float*)d_out;

    const int E = in_sizes[1] / 2;
    const int* src = ei;
    const int* dst = ei + E;
    const int N = N_NODES;

    // workspace layout (intermediates in bf16)
    unsigned short* bufA = (unsigned short*)d_ws;       // N*128 bf16
    unsigned short* bufB = bufA + (size_t)N * 128;      // N*128 bf16
    float* dinv      = (float*)(bufB + (size_t)N * 128); // N f32
    unsigned* bucket = (unsigned*)(dinv + N);            // E (packed dloc<<24|src) — live through all gathers
    int*   tot       = (int*)(bucket + E);               // NBUCK
    int*   base      = tot + NBUCK;                      // NBUCK+1

    auto cdiv = [](long long a, long long b) { return (int)((a + b - 1) / b); };
    const int NBLK = cdiv(E, EPB);  // 196 for E=1.6M (must be <= 512)

    // counts/pos alias bufA (dead until gemm1; bucketing finishes first)
    int* counts = (int*)bufA;                 // NBLK*NBUCK ints
    int* pos    = counts + (size_t)NBLK * NBUCK;

    const int GB = cdiv(N, 64);  // mfma gemm grid (64 rows/block)

    // ---- edge bucketing: counting sort by 128-node bucket, zero global atomics ----
    count_edges<<<NBLK, 512, 0, stream>>>(dst, counts, E);
    scan_pos<<<NBUCK, 512, 0, stream>>>(counts, pos, tot, NBLK);
    scan_base<<<1, 1024, 0, stream>>>(tot, base, E);
    place_edges<<<NBLK, 512, 0, stream>>>(src, dst, pos, base, bucket, E);
    deg_dinv<<<NBUCK, 256, 0, stream>>>(bucket, base, dinv, N);

    // ---- Layer 1: xs0 = dinv*(x @ W1) (128->64, fp32 in); h1s = dinv*LN_ELU(gather + b1) ----
    mfma_gemm<128, 64, false, false, true, false, true><<<GB, 256, 0, stream>>>(
        x, W1, nullptr, nullptr, nullptr, bufA, N, dinv);
    gather_lds<true, true><<<NBUCK, 256, 0, stream>>>(bufA, bucket, base, dinv, b1, g1, be1, bufB, N);

    // ---- Layer 2 (aggregate-first): a2 = gather(h1s); h2 = LN_ELU(a2 @ W2 + b2) ----
    gather_lds<false, false><<<NBUCK, 256, 0, stream>>>(bufB, bucket, base, dinv, nullptr, nullptr, nullptr, bufA, N);
    mfma_gemm<64, 128, true, true, false, false, false><<<GB, 256, 0, stream>>>(
        bufA, W2, b2, g2, be2, bufB, N, nullptr);

    // ---- Layer 3: xs2 = dinv*(h2 @ W3) (128->64); h3 = LN_ELU(gather + b3) ----
    mfma_gemm<128, 64, false, false, false, false, true><<<GB, 256, 0, stream>>>(
        bufB, W3, nullptr, nullptr, nullptr, bufA, N, dinv);
    gather_lds<true, false><<<NBUCK, 256, 0, stream>>>(bufA, bucket, base, dinv, b3, g3, be3, bufB, N);

    // ---- lin1: t = LN_ELU(h3 @ lw1 + lb1) (64->32) ----
    mfma_gemm<64, 32, true, true, false, false, false><<<GB, 256, 0, stream>>>(
        bufB, lw1, lb1, g4, be4, bufA, N, nullptr);

    // ---- lin2: out = t @ lw2 + lb2 (32->32, fp32 out) ----
    mfma_gemm<32, 32, false, true, false, true, false><<<GB, 256, 0, stream>>>(
        bufA, lw2, lb2, nullptr, nullptr, out, N, nullptr);
}

// Round 7
// 361.927 us; speedup vs baseline: 6.2378x; 6.2378x over previous
//
#include <hip/hip_runtime.h>
#include <math.h>

#define N_NODES 100000
#define LN_EPS 1e-5f
#define NBUCK ((N_NODES + 255) / 256)  // 391 buckets of 256 nodes
#define EPB 8192                        // edges per block in count/place

typedef __attribute__((ext_vector_type(8))) short bf16x8;
typedef __attribute__((ext_vector_type(4))) float f32x4;

__device__ __forceinline__ unsigned short f2bf(float f) {
    unsigned int u = __float_as_uint(f);
    return (unsigned short)((u + 0x7FFFu + ((u >> 16) & 1u)) >> 16);
}
__device__ __forceinline__ float bf2f(unsigned short u) {
    return __uint_as_float(((unsigned int)u) << 16);
}

// ======== atomic-free CSR build (counting sort by 256-node bucket) ========
// R1 lesson: E global-scope atomics cost ~42B HBM write per edge; all
// conflict resolution stays in LDS, placement is deterministic via scans.
// R6 lesson: gather must keep a huge grid (25k blocks) — the 782-block
// edge-centric variant collapsed TLP (occ 20%, VALU 6%) and ran 11x slower.

// K1: per-block histogram of dst buckets -> counts[blk][bucket]
__global__ void count_edges(const int* __restrict__ dst, int* __restrict__ counts, int E) {
    __shared__ int hist[NBUCK];
    for (int b = threadIdx.x; b < NBUCK; b += 512) hist[b] = 0;
    __syncthreads();
    int e0 = blockIdx.x * EPB;
#pragma unroll 4
    for (int i = 0; i < EPB / 512; ++i) {
        int e = e0 + i * 512 + (int)threadIdx.x;
        if (e < E) atomicAdd(&hist[((unsigned)dst[e]) >> 8], 1);
    }
    __syncthreads();
    for (int b = threadIdx.x; b < NBUCK; b += 512)
        counts[blockIdx.x * NBUCK + b] = hist[b];
}

// K2: per-bucket exclusive scan across blocks -> pos[blk][bucket], tot[bucket]
__global__ void scan_pos(const int* __restrict__ counts, int* __restrict__ pos,
                         int* __restrict__ tot, int nblk) {
    __shared__ int s[512];
    int b = blockIdx.x, i = threadIdx.x;
    int v = (i < nblk) ? counts[i * NBUCK + b] : 0;
    s[i] = v;
    __syncthreads();
    for (int off = 1; off < 512; off <<= 1) {
        int t = (i >= off) ? s[i - off] : 0;
        __syncthreads();
        s[i] += t;
        __syncthreads();
    }
    if (i < nblk) pos[i * NBUCK + b] = s[i] - v;
    if (i == 511) tot[b] = s[511];
}

// K3: exclusive scan of bucket totals -> base[bucket], base[NBUCK]=E
__global__ void scan_base(const int* __restrict__ tot, int* __restrict__ base, int E) {
    __shared__ int s[512];
    int i = threadIdx.x;
    int v = (i < NBUCK) ? tot[i] : 0;
    s[i] = v;
    __syncthreads();
    for (int off = 1; off < 512; off <<= 1) {
        int t = (i >= off) ? s[i - off] : 0;
        __syncthreads();
        s[i] += t;
        __syncthreads();
    }
    if (i < NBUCK) base[i] = s[i] - v;
    if (i == 0) base[NBUCK] = E;
}

// K4: place edges into per-(block,bucket) disjoint slabs via LDS cursors.
__global__ void place_edges(const int* __restrict__ src, const int* __restrict__ dst,
                            const int* __restrict__ pos, const int* __restrict__ base,
                            unsigned* __restrict__ bucket, int E) {
    __shared__ int lcur[NBUCK];
    for (int b = threadIdx.x; b < NBUCK; b += 512)
        lcur[b] = pos[blockIdx.x * NBUCK + b] + base[b];
    __syncthreads();
    int e0 = blockIdx.x * EPB;
#pragma unroll 4
    for (int i = 0; i < EPB / 512; ++i) {
        int e = e0 + i * 512 + (int)threadIdx.x;
        if (e < E) {
            unsigned d = (unsigned)dst[e];
            unsigned s = (unsigned)src[e];
            int p = atomicAdd(&lcur[d >> 8], 1);
            bucket[p] = ((d & 255u) << 24) | s;
        }
    }
}

// K5: one block per bucket: slab histogram -> degree/dinv/offsets (fused),
// then scatter csr within the block's private 16KB window via LDS cursors.
__global__ void build_csr_node(const unsigned* __restrict__ bucket, const int* __restrict__ base,
                               int* __restrict__ offsets, float* __restrict__ dinv,
                               int* __restrict__ csr, int E) {
    __shared__ int hist[256];
    __shared__ int cur[256];
    int b = blockIdx.x, t = threadIdx.x;
    int r0 = b << 8;
    hist[t] = 0;
    __syncthreads();
    int s0 = base[b], s1 = base[b + 1];
    for (int e = s0 + t; e < s1; e += 256)
        atomicAdd(&hist[bucket[e] >> 24], 1);
    __syncthreads();
    int deg = hist[t];
    for (int off = 1; off < 256; off <<= 1) {
        int tv = (t >= off) ? hist[t - off] : 0;
        __syncthreads();
        hist[t] += tv;
        __syncthreads();
    }
    int excl = hist[t] - deg;  // exclusive scan within bucket
    int node = r0 + t;
    if (node < N_NODES) {
        offsets[node] = s0 + excl;
        dinv[node] = rsqrtf((float)deg + 1.f);
        cur[t] = s0 + excl;
    }
    if (node == N_NODES - 1) offsets[N_NODES] = E;
    __syncthreads();
    for (int e = s0 + t; e < s1; e += 256) {
        unsigned u = bucket[e];
        int p = atomicAdd(&cur[u >> 24], 1);  // LDS atomic, window is L1/L2-hot
        csr[p] = (int)(u & 0xFFFFFFu);
    }
}

// ---------------- MFMA bf16 gemm: Y = X[n,K] @ W[K,OUT] (+bias, +LN+ELU, +dinv row scale) ----
template <int K, int OUT, bool LN, bool BIAS, bool AF32, bool OF32, bool SCALED>
__launch_bounds__(256)
__global__ void mfma_gemm(const void* __restrict__ Xv, const float* __restrict__ W,
                          const float* __restrict__ bias, const float* __restrict__ gamma,
                          const float* __restrict__ beta, void* __restrict__ Yv, int n,
                          const float* __restrict__ dinvp) {
    constexpr int T  = OUT / 16;
    constexpr int KP = K + 8;

    __shared__ __align__(16) unsigned short sWT[OUT * KP];  // W^T bf16
    for (int i = threadIdx.x; i < K * OUT; i += 256) {
        int k = i / OUT, o = i - k * OUT;
        sWT[o * KP + k] = f2bf(W[i]);
    }
    __syncthreads();

    int wv = threadIdx.x >> 6, lane = threadIdx.x & 63;
    int quad = lane >> 4, l16 = lane & 15;
    int m0 = (blockIdx.x * 4 + wv) * 16;
    int rowc = min(m0 + l16, n - 1);

    f32x4 acc[T];
#pragma unroll
    for (int t = 0; t < T; ++t) acc[t] = (f32x4){0.f, 0.f, 0.f, 0.f};

#pragma unroll
    for (int s = 0; s < K / 32; ++s) {
        int koff = s * 32 + quad * 8;
        bf16x8 af;
        if (AF32) {
            const float4* X4 = (const float4*)Xv;
            size_t base = ((size_t)rowc * K + koff) >> 2;
            float4 a0 = X4[base];
            float4 a1 = X4[base + 1];
            af[0] = (short)f2bf(a0.x); af[1] = (short)f2bf(a0.y);
            af[2] = (short)f2bf(a0.z); af[3] = (short)f2bf(a0.w);
            af[4] = (short)f2bf(a1.x); af[5] = (short)f2bf(a1.y);
            af[6] = (short)f2bf(a1.z); af[7] = (short)f2bf(a1.w);
        } else {
            const unsigned short* Xb = (const unsigned short*)Xv;
            af = *(const bf16x8*)(Xb + (size_t)rowc * K + koff);
        }
#pragma unroll
        for (int t = 0; t < T; ++t) {
            const bf16x8 bfrag = *(const bf16x8*)&sWT[(t * 16 + l16) * KP + koff];
            acc[t] = __builtin_amdgcn_mfma_f32_16x16x32_bf16(af, bfrag, acc[t], 0, 0, 0);
        }
    }

    float bj[T], gj[T], btj[T];
#pragma unroll
    for (int t = 0; t < T; ++t) {
        int c = t * 16 + l16;
        bj[t]  = BIAS ? bias[c] : 0.f;
        gj[t]  = LN ? gamma[c] : 1.f;
        btj[t] = LN ? beta[c] : 0.f;
    }

    float* Yf = (float*)Yv;
    unsigned short* Yb = (unsigned short*)Yv;

    if (LN) {
        float s[4] = {0.f, 0.f, 0.f, 0.f}, sq[4] = {0.f, 0.f, 0.f, 0.f};
#pragma unroll
        for (int t = 0; t < T; ++t)
#pragma unroll
            for (int r = 0; r < 4; ++r) {
                float v = acc[t][r] + bj[t];
                s[r] += v;
                sq[r] += v * v;
            }
#pragma unroll
        for (int off = 1; off < 16; off <<= 1)
#pragma unroll
            for (int r = 0; r < 4; ++r) {
                s[r] += __shfl_xor(s[r], off, 64);
                sq[r] += __shfl_xor(sq[r], off, 64);
            }
        float mu[4], rs[4];
#pragma unroll
        for (int r = 0; r < 4; ++r) {
            mu[r] = s[r] / OUT;
            float var = sq[r] / OUT - mu[r] * mu[r];
            rs[r] = rsqrtf(var + LN_EPS);
        }
#pragma unroll
        for (int r = 0; r < 4; ++r) {
            int rowg = m0 + quad * 4 + r;
            if (rowg < n) {
                float dv = SCALED ? dinvp[rowg] : 1.f;
#pragma unroll
                for (int t = 0; t < T; ++t) {
                    float y = (acc[t][r] + bj[t] - mu[r]) * rs[r] * gj[t] + btj[t];
                    y = y > 0.f ? y : expm1f(y);
                    if (SCALED) y *= dv;
                    size_t idx = (size_t)rowg * OUT + t * 16 + l16;
                    if (OF32) Yf[idx] = y; else Yb[idx] = f2bf(y);
                }
            }
        }
    } else {
#pragma unroll
        for (int r = 0; r < 4; ++r) {
            int rowg = m0 + quad * 4 + r;
            if (rowg < n) {
                float dv = SCALED ? dinvp[rowg] : 1.f;
#pragma unroll
                for (int t = 0; t < T; ++t) {
                    float y = acc[t][r] + bj[t];
                    if (SCALED) y *= dv;
                    size_t idx = (size_t)rowg * OUT + t * 16 + l16;
                    if (OF32) Yf[idx] = y; else Yb[idx] = f2bf(y);
                }
            }
        }
    }
}

// ---------------- gather v7: v5 pipeline + FORCED wave-uniformity ----------------
// R5 post-mortem arithmetic: 83% VALUBusy at 62us = ~40 VALU inst/edge, vs ~5
// in the loop body. The excess is readlane WATERFALL loops: idx derives from
// offsets[node] where node depends on threadIdx>>6, which divergence analysis
// can't prove wave-uniform. Fix: pass beg/end through readfirstlane -> all of
// m/k/e/idx become provably SGPR-uniform -> v_readlane with SGPR index (no
// waterfall), clamp/weight become s_cselect, loop control goes scalar.
// Structure unchanged from v5: chunks of 16 edges, 16 back-to-back
// global_load_ushort (scalar row base), ONE vmcnt drain, masked FMAs.
// Input xs PRE-SCALED by dinv[row]:
//   out = dinv[node] * (sum_{s in N(node)} xs[s] + xs[node])
template <bool LN, bool SCALEOUT>
__launch_bounds__(256)
__global__ void gather_d(const unsigned short* __restrict__ xs, const int* __restrict__ offsets,
                         const int* __restrict__ csr_src, const float* __restrict__ dinv,
                         const float* __restrict__ bias, const float* __restrict__ gamma,
                         const float* __restrict__ beta, unsigned short* __restrict__ out, int n) {
    int wave = threadIdx.x >> 6;
    int lane = threadIdx.x & 63;
    int node = blockIdx.x * (blockDim.x >> 6) + wave;
    if (node >= n) return;
    // force wave-uniform scalars into SGPRs (kills readlane waterfalls)
    int beg = __builtin_amdgcn_readfirstlane(offsets[node]);
    int end = __builtin_amdgcn_readfirstlane(offsets[node + 1]);

    float a0 = 0.f, a1 = 0.f, a2 = 0.f, a3 = 0.f;
    for (int base = beg; base < end; base += 64) {
        int m = min(64, end - base);   // uniform (SGPR)
        int myS = (lane < m) ? csr_src[base + lane] : 0;
        for (int k = 0; k < m; k += 16) {
            unsigned short v[16];
            float w[16];
            // issue phase: 16 independent loads, SGPR row base, no waits
#pragma unroll
            for (int j = 0; j < 16; ++j) {
                int e = k + j;                 // uniform
                int idx = (e < m) ? e : 0;     // s_cselect, clamp to valid edge
                int s = __builtin_amdgcn_readlane(myS, idx);  // single v_readlane
                v[j] = xs[((size_t)(unsigned)s << 6) + lane];
                w[j] = (e < m) ? 1.f : 0.f;
            }
            // consume phase: one vmcnt drain, then pure VALU
#pragma unroll
            for (int j = 0; j < 16; ++j) {
                float f = bf2f(v[j]) * w[j];
                if ((j & 3) == 0) a0 += f;
                else if ((j & 3) == 1) a1 += f;
                else if ((j & 3) == 2) a2 += f;
                else a3 += f;
            }
        }
    }

    float dd = dinv[node];
    float self = bf2f(xs[((size_t)(unsigned)node << 6) + lane]);
    float y = (a0 + a1 + a2 + a3 + self) * dd;

    if (!LN) {
        out[((size_t)(unsigned)node << 6) + lane] = f2bf(y);
        return;
    }
    float yb = y + bias[lane];
    float s = yb, sq = yb * yb;
#pragma unroll
    for (int off = 1; off < 64; off <<= 1) {
        s += __shfl_xor(s, off, 64);
        sq += __shfl_xor(sq, off, 64);
    }
    float mu = s * (1.f / 64.f);
    float var = sq * (1.f / 64.f) - mu * mu;
    float rs = rsqrtf(var + LN_EPS);
    float z = (yb - mu) * rs * gamma[lane] + beta[lane];
    z = z > 0.f ? z : expm1f(z);
    if (SCALEOUT) z *= dd;  // produce xs for the next gather
    out[((size_t)(unsigned)node << 6) + lane] = f2bf(z);
}

extern "C" void kernel_launch(void* const* d_in, const int* in_sizes, int n_in,
                              void* d_out, int out_size, void* d_ws, size_t ws_size,
                              hipStream_t stream) {
    const float* x  = (const float*)d_in[0];
    const int* ei   = (const int*)d_in[1];
    const float* W1 = (const float*)d_in[2];
    const float* b1 = (const float*)d_in[3];
    const float* g1 = (const float*)d_in[4];
    const float* be1= (const float*)d_in[5];
    const float* W2 = (const float*)d_in[6];
    const float* b2 = (const float*)d_in[7];
    const float* g2 = (const float*)d_in[8];
    const float* be2= (const float*)d_in[9];
    const float* W3 = (const float*)d_in[10];
    const float* b3 = (const float*)d_in[11];
    const float* g3 = (const float*)d_in[12];
    const float* be3= (const float*)d_in[13];
    const float* lw1= (const float*)d_in[14];
    const float* lb1= (const float*)d_in[15];
    const float* g4 = (const float*)d_in[16];
    const float* be4= (const float*)d_in[17];
    const float* lw2= (const float*)d_in[18];
    const float* lb2= (const float*)d_in[19];
    float* out = (float*)d_out;

    const int E = in_sizes[1] / 2;
    const int* src = ei;
    const int* dst = ei + E;
    const int N = N_NODES;

    // workspace layout (intermediates in bf16)
    unsigned short* bufA = (unsigned short*)d_ws;       // N*128 bf16
    unsigned short* bufB = bufA + (size_t)N * 128;      // N*128 bf16
    float* dinv    = (float*)(bufB + (size_t)N * 128);  // N f32
    int*   offsets = (int*)(dinv + N);                  // N+1
    int*   csr     = offsets + N + 1;                   // E
    int*   tot     = csr + E;                           // NBUCK
    int*   base    = tot + NBUCK;                       // NBUCK+1

    auto cdiv = [](long long a, long long b) { return (int)((a + b - 1) / b); };
    const int NBLK = cdiv(E, EPB);  // 196 for E=1.6M (must be <= 512)

    // counts/pos alias bufA (dead until gemm1); bucket aliases bufB (dead
    // until gather1 writes it).
    int* counts = (int*)bufA;                 // NBLK*NBUCK ints
    int* pos    = counts + (size_t)NBLK * NBUCK;
    unsigned* bucket = (unsigned*)bufB;       // E * 4B (packed dloc<<24|src)

    const int GB = cdiv(N, 64);  // mfma gemm grid (64 rows/block)

    // ---- CSR build: counting sort, zero global atomics ----
    count_edges<<<NBLK, 512, 0, stream>>>(dst, counts, E);
    scan_pos<<<NBUCK, 512, 0, stream>>>(counts, pos, tot, NBLK);
    scan_base<<<1, 512, 0, stream>>>(tot, base, E);
    place_edges<<<NBLK, 512, 0, stream>>>(src, dst, pos, base, bucket, E);
    build_csr_node<<<NBUCK, 256, 0, stream>>>(bucket, base, offsets, dinv, csr, E);

    // ---- Layer 1: xs0 = dinv*(x @ W1) (128->64, fp32 in); h1s = dinv*LN_ELU(gather + b1) ----
    mfma_gemm<128, 64, false, false, true, false, true><<<GB, 256, 0, stream>>>(
        x, W1, nullptr, nullptr, nullptr, bufA, N, dinv);
    gather_d<true, true><<<cdiv(N, 4), 256, 0, stream>>>(bufA, offsets, csr, dinv, b1, g1, be1, bufB, N);

    // ---- Layer 2 (aggregate-first): a2 = gather(h1s); h2 = LN_ELU(a2 @ W2 + b2) ----
    gather_d<false, false><<<cdiv(N, 4), 256, 0, stream>>>(bufB, offsets, csr, dinv, nullptr, nullptr, nullptr, bufA, N);
    mfma_gemm<64, 128, true, true, false, false, false><<<GB, 256, 0, stream>>>(
        bufA, W2, b2, g2, be2, bufB, N, nullptr);

    // ---- Layer 3: xs2 = dinv*(h2 @ W3) (128->64); h3 = LN_ELU(gather + b3) ----
    mfma_gemm<128, 64, false, false, false, false, true><<<GB, 256, 0, stream>>>(
        bufB, W3, nullptr, nullptr, nullptr, bufA, N, dinv);
    gather_d<true, false><<<cdiv(N, 4), 256, 0, stream>>>(bufA, offsets, csr, dinv, b3, g3, be3, bufB, N);

    // ---- lin1: t = LN_ELU(h3 @ lw1 + lb1) (64->32) ----
    mfma_gemm<64, 32, true, true, false, false, false><<<GB, 256, 0, stream>>>(
        bufB, lw1, lb1, g4, be4, bufA, N, nullptr);

    // ---- lin2: out = t @ lw2 + lb2 (32->32, fp32 out) ----
    mfma_gemm<32, 32, false, true, false, true, false><<<GB, 256, 0, stream>>>(
        bufA, lw2, lb2, nullptr, nullptr, out, N, nullptr);
}